// Round 5
// baseline (432.489 us; speedup 1.0000x reference)
//
#include <hip/hip_runtime.h>

#define T_LEN 1024
#define M_DIM 128
#define B_NUM 64

// One block (256 thr, 4 waves) per batch. Lane = (igrp = lane&7, jq-within-wave
// = (lane>>3)&7). Lane owns outputs j0..j0+3 (j0 = (wid*8+jql)*4) and holds the
// W block w[i in igrp*16..+15][j0..j0+3] = 64 VGPRs. Per step it reads only its
// 16 u values (4x ds_read_b128, slot-rotated so bank aliasing is <=2-way =
// free), does 64 FMAs into 4 accumulators, butterfly-reduces over the 8
// i-groups (d=1,2,4), scales by exp(P_t) (and lagged 1/Z every 4 steps), and
// designated lanes write the u quad back. This cuts LDS->RF delivery from
// 64KB/step (round-4 wall, ~770 cyc) to 16KB/step.
// In-loop barriers are s_waitcnt lgkmcnt(0) + s_barrier (no vmcnt drain), so
// the 8-row P prefetch burst stays in flight across barriers (counted vmcnt at
// each consumption). Path score sY hoisted (no sequential dependency).
__global__ __launch_bounds__(256, 1) void crf_fwd(
    const float* __restrict__ P, const float* __restrict__ A,
    const int* __restrict__ Y, const int* __restrict__ L,
    float* __restrict__ out)
{
  const int b    = blockIdx.x;
  const int tid  = threadIdx.x;
  const int lane = tid & 63;
  const int wid  = tid >> 6;        // 0..3
  const int igrp = lane & 7;        // i-group: i = igrp*16 .. +15
  const int jql  = (lane >> 3) & 7; // j-quad within wave (lane bits 3..5)
  const int jq   = wid * 8 + jql;   // global j-quad 0..31
  const int j0   = jq * 4;

  __shared__ __align__(16) float u_lds[2][M_DIM];
  __shared__ __align__(16) float red[4];      // per-wave max snapshots
  __shared__ float red_sum[4];
  __shared__ float sY_sh[4];

  const int Lb = L[b];
  const float* Pb = P + (size_t)b * T_LEN * M_DIM;
  const int*   Yb = Y + b * T_LEN;

#define BARRIER_RELAXED() do { \
    asm volatile("s_waitcnt lgkmcnt(0)" ::: "memory"); \
    __builtin_amdgcn_s_barrier(); } while (0)

  // W block in regs: w[(k*4+e)*4+jj] = exp(A[igrp*16 + ((k+igrp)&3)*4 + e][j0+jj])
  float w[64];
  #pragma unroll
  for (int k = 0; k < 4; ++k) {
    const int slot = (k + igrp) & 3;
    #pragma unroll
    for (int e = 0; e < 4; ++e) {
      const int i = igrp * 16 + slot * 4 + e;
      #pragma unroll
      for (int jj = 0; jj < 4; ++jj)
        w[(k * 4 + e) * 4 + jj] = __expf(A[i * M_DIM + j0 + jj]);
    }
  }

  // ---- path score sY: no sequential dependency, gather in parallel ----
  float mySY = 0.f;
  for (int tt = tid; tt < Lb; tt += 256) {
    int yt = Yb[tt];
    float term = Pb[tt * M_DIM + yt];
    term += (tt == 0) ? A[M_DIM * M_DIM + yt] : A[Yb[tt - 1] * M_DIM + yt];
    mySY += term;
  }
  #pragma unroll
  for (int d = 1; d < 64; d <<= 1) mySY += __shfl_xor(mySY, d);
  if (lane == 0) sY_sh[wid] = mySY;

  // ---- t = 0 ----
  float4 p0 = *(const float4*)(Pb + j0);
  float4 as = *(const float4*)(A + M_DIM * M_DIM + j0);
  float4 un;
  un.x = __expf(p0.x + as.x); un.y = __expf(p0.y + as.y);
  un.z = __expf(p0.z + as.z); un.w = __expf(p0.w + as.w);
  if (igrp == 0) *(float4*)&u_lds[0][j0] = un;
  {
    float zm = fmaxf(fmaxf(un.x, un.y), fmaxf(un.z, un.w));
    #pragma unroll
    for (int d = 8; d < 64; d <<= 1) zm = fmaxf(zm, __shfl_xor(zm, d));
    if (lane == 0) red[wid] = zm;   // snapshot, applied at t=1
  }
  float C = 0.f;
  float4 p_cur = *(const float4*)(Pb + M_DIM + j0);   // row t=1 (always valid)
  if (Lb == 1) {
    float zs = (igrp == 0) ? (un.x + un.y) + (un.z + un.w) : 0.f;
    #pragma unroll
    for (int d = 1; d < 64; d <<= 1) zs += __shfl_xor(zs, d);
    if (lane == 0) red_sum[wid] = zs;
  }
  __syncthreads();

  if (Lb == 1) {
    if (tid == 0) {
      float s  = (red_sum[0] + red_sum[1]) + (red_sum[2] + red_sum[3]);
      float sy = (sY_sh[0] + sY_sh[1]) + (sY_sh[2] + sY_sh[3]);
      out[b] = __logf(s) - sy;
    }
    return;
  }

// Sub-step. MODE: 0 = plain, 1 = APPLY renorm (t%4==1), 2 = SNAP (t%4==0).
#define CRF_STEP(S, MODE, PNEXT)                                           \
  {                                                                        \
    float4 ep;                                                             \
    ep.x = __expf(p_cur.x); ep.y = __expf(p_cur.y);                        \
    ep.z = __expf(p_cur.z); ep.w = __expf(p_cur.w);                        \
    if ((MODE) == 1) {                                                     \
      float4 rz = *(const float4*)red;                                     \
      float Z = fmaxf(fmaxf(rz.x, rz.y), fmaxf(rz.z, rz.w));               \
      C += __logf(Z);                                                      \
      float iZ = __builtin_amdgcn_rcpf(Z);                                 \
      ep.x *= iZ; ep.y *= iZ; ep.z *= iZ; ep.w *= iZ;                      \
    }                                                                      \
    const float4* u4 = (const float4*)(u_lds[cur]);                        \
    float acc[4] = {0.f, 0.f, 0.f, 0.f};                                   \
    _Pragma("unroll")                                                      \
    for (int k = 0; k < 4; ++k) {                                          \
      float4 uu = u4[igrp * 4 + ((k + igrp) & 3)];                         \
      const float ue[4] = {uu.x, uu.y, uu.z, uu.w};                        \
      _Pragma("unroll")                                                    \
      for (int e = 0; e < 4; ++e) {                                        \
        _Pragma("unroll")                                                  \
        for (int jj = 0; jj < 4; ++jj)                                     \
          acc[jj] = fmaf(ue[e], w[(k * 4 + e) * 4 + jj], acc[jj]);         \
      }                                                                    \
    }                                                                      \
    _Pragma("unroll")                                                      \
    for (int jj = 0; jj < 4; ++jj) {                                       \
      acc[jj] += __shfl_xor(acc[jj], 1);                                   \
      acc[jj] += __shfl_xor(acc[jj], 2);                                   \
      acc[jj] += __shfl_xor(acc[jj], 4);                                   \
    }                                                                      \
    un.x = acc[0] * ep.x; un.y = acc[1] * ep.y;                            \
    un.z = acc[2] * ep.z; un.w = acc[3] * ep.w;                            \
    if (igrp == 0) *(float4*)&u_lds[cur ^ 1][j0] = un;                     \
    const bool last_ = (tb + (S) == Lb - 1);                               \
    if (last_) {                                                           \
      float zs = (igrp == 0) ? (un.x + un.y) + (un.z + un.w) : 0.f;        \
      _Pragma("unroll")                                                    \
      for (int d = 1; d < 64; d <<= 1) zs += __shfl_xor(zs, d);            \
      if (lane == 0) red_sum[wid] = zs;                                    \
    } else if ((MODE) == 2) {                                              \
      float zm = fmaxf(fmaxf(un.x, un.y), fmaxf(un.z, un.w));              \
      _Pragma("unroll")                                                    \
      for (int d = 8; d < 64; d <<= 1) zm = fmaxf(zm, __shfl_xor(zm, d));  \
      if (lane == 0) red[wid] = zm;                                        \
    }                                                                      \
    BARRIER_RELAXED();                                                     \
    if (last_) goto finish;                                                \
    p_cur = (PNEXT);                                                       \
    cur ^= 1;                                                              \
  }

  {
    int cur = 0;
    int tb  = 1;   // iteration handles steps tb..tb+7
    const float* Pq = Pb + j0;
    for (;;) {
      // Burst-prefetch P rows tb+1..tb+8 (clamped) into static float4 regs.
      float4 pn0, pn1, pn2, pn3, pn4, pn5, pn6, pn7;
      {
        int r;
        r = tb + 1; r = r < T_LEN ? r : T_LEN - 1; pn0 = *(const float4*)(Pq + r * M_DIM);
        r = tb + 2; r = r < T_LEN ? r : T_LEN - 1; pn1 = *(const float4*)(Pq + r * M_DIM);
        r = tb + 3; r = r < T_LEN ? r : T_LEN - 1; pn2 = *(const float4*)(Pq + r * M_DIM);
        r = tb + 4; r = r < T_LEN ? r : T_LEN - 1; pn3 = *(const float4*)(Pq + r * M_DIM);
        r = tb + 5; r = r < T_LEN ? r : T_LEN - 1; pn4 = *(const float4*)(Pq + r * M_DIM);
        r = tb + 6; r = r < T_LEN ? r : T_LEN - 1; pn5 = *(const float4*)(Pq + r * M_DIM);
        r = tb + 7; r = r < T_LEN ? r : T_LEN - 1; pn6 = *(const float4*)(Pq + r * M_DIM);
        r = tb + 8; r = r < T_LEN ? r : T_LEN - 1; pn7 = *(const float4*)(Pq + r * M_DIM);
      }
      // t mod 4 over sub-steps: 1,2,3,0,1,2,3,0
      CRF_STEP(0, 1, pn0)
      CRF_STEP(1, 0, pn1)
      CRF_STEP(2, 0, pn2)
      CRF_STEP(3, 2, pn3)
      CRF_STEP(4, 1, pn4)
      CRF_STEP(5, 0, pn5)
      CRF_STEP(6, 0, pn6)
      CRF_STEP(7, 2, pn7)
      tb += 8;
    }
  }

finish:
  if (tid == 0) {
    float s  = (red_sum[0] + red_sum[1]) + (red_sum[2] + red_sum[3]);
    float sy = (sY_sh[0] + sY_sh[1]) + (sY_sh[2] + sY_sh[3]);
    out[b] = __logf(s) + C - sy;
  }
}

extern "C" void kernel_launch(void* const* d_in, const int* in_sizes, int n_in,
                              void* d_out, int out_size, void* d_ws, size_t ws_size,
                              hipStream_t stream) {
  const float* P = (const float*)d_in[0];
  const float* A = (const float*)d_in[1];
  const int*   Y = (const int*)d_in[2];
  const int*   L = (const int*)d_in[3];
  float* o = (float*)d_out;
  hipLaunchKernelGGL(crf_fwd, dim3(B_NUM), dim3(256), 0, stream, P, A, Y, L, o);
}

// Round 6
// 410.711 us; speedup vs baseline: 1.0530x; 1.0530x over previous
//
#include <hip/hip_runtime.h>

#define T_LEN 1024
#define M_DIM 128
#define B_NUM 64

// DPP-based add over lane groups (VALU pipe only — no ds_swizzle/bpermute).
// 0xB1 = quad_perm [1,0,3,2] (xor1), 0x4E = quad_perm [2,3,0,1] (xor2),
// 0x141 = row_half_mirror (xor7 within 8; valid once quads are uniform),
// 0x140 = row_mirror (xor15 within 16; valid once 8-groups are uniform).
template<int CTRL>
__device__ __forceinline__ float dpp_add(float x) {
  int y = __builtin_amdgcn_update_dpp(0, __float_as_int(x), CTRL, 0xf, 0xf, true);
  return x + __int_as_float(y);
}

// One block (512 thr, 8 waves) per batch. Lane = (igrp = lane&15, jql =
// (lane>>4)&3); jq = wid*4+jql; lane owns outputs j0..j0+3 (j0=jq*4) and
// holds w[i in igrp*8..+7][j0..j0+3] = 32 VGPRs (w[32] is the size proven
// to stay in registers; w[64] spilled in rounds 2/5). Per step: 2x broadcast
// ds_read_b128 (slot f = igrp*2 + (((igrp>>2)&1)^q): the 16 addresses cover
// each bank-quad residue mod 8 exactly twice -> 2-way = free), 32 FMAs into
// acc[4], 4-stage DPP reduce over the 16 i-groups, scale by exp(P_t) (and
// lagged 1/Z every 4 steps), igrp==0 lanes write the u quad. LDS->RF
// delivery: 16 KB/step vs round-4's 64 KB/step (its ~770cyc wall).
// Relaxed in-loop barrier (lgkmcnt only) keeps the 8-row P burst in flight.
__global__ __launch_bounds__(512, 2) void crf_fwd(
    const float* __restrict__ P, const float* __restrict__ A,
    const int* __restrict__ Y, const int* __restrict__ L,
    float* __restrict__ out)
{
  const int b    = blockIdx.x;
  const int tid  = threadIdx.x;
  const int lane = tid & 63;
  const int wid  = tid >> 6;          // 0..7
  const int igrp = lane & 15;         // i-group: i = igrp*8 .. +7
  const int jql  = (lane >> 4) & 3;   // j-quad within wave
  const int jq   = wid * 4 + jql;     // global j-quad 0..31
  const int j0   = jq * 4;
  const int s    = (igrp >> 2) & 1;   // bank-spread bit
  const int f0   = igrp * 2 + s;      // first read slot (float4 units)
  const int f1   = igrp * 2 + (s ^ 1);

  __shared__ __align__(16) float u_lds[2][M_DIM];
  __shared__ __align__(16) float red[8];   // per-wave max snapshots
  __shared__ float red_sum[8];
  __shared__ float sY_sh[8];

  const int Lb = L[b];
  const float* Pb = P + (size_t)b * T_LEN * M_DIM;
  const int*   Yb = Y + b * T_LEN;

#define BARRIER_RELAXED() do { \
    asm volatile("s_waitcnt lgkmcnt(0)" ::: "memory"); \
    __builtin_amdgcn_s_barrier(); } while (0)

  // w in read order: w[q*16 + e*4 + jj] = exp(A[igrp*8 + ((s^q)<<2) + e][j0+jj])
  float w[32];
  #pragma unroll
  for (int q = 0; q < 2; ++q) {
    #pragma unroll
    for (int e = 0; e < 4; ++e) {
      const int i = igrp * 8 + ((s ^ q) << 2) + e;
      #pragma unroll
      for (int jj = 0; jj < 4; ++jj)
        w[q * 16 + e * 4 + jj] = __expf(A[i * M_DIM + j0 + jj]);
    }
  }

  // ---- path score sY: no sequential dependency, gather in parallel ----
  float mySY = 0.f;
  for (int tt = tid; tt < Lb; tt += 512) {
    int yt = Yb[tt];
    float term = Pb[tt * M_DIM + yt];
    term += (tt == 0) ? A[M_DIM * M_DIM + yt] : A[Yb[tt - 1] * M_DIM + yt];
    mySY += term;
  }
  #pragma unroll
  for (int d = 1; d < 64; d <<= 1) mySY += __shfl_xor(mySY, d);
  if (lane == 0) sY_sh[wid] = mySY;

  // ---- t = 0 ----
  float4 p0 = *(const float4*)(Pb + j0);
  float4 as = *(const float4*)(A + M_DIM * M_DIM + j0);
  float4 un;
  un.x = __expf(p0.x + as.x); un.y = __expf(p0.y + as.y);
  un.z = __expf(p0.z + as.z); un.w = __expf(p0.w + as.w);
  if (igrp == 0) *(float4*)&u_lds[0][j0] = un;
  {
    float zm = fmaxf(fmaxf(un.x, un.y), fmaxf(un.z, un.w));
    zm = fmaxf(zm, __shfl_xor(zm, 16));
    zm = fmaxf(zm, __shfl_xor(zm, 32));
    if (lane == 0) red[wid] = zm;   // snapshot, applied at t=1
  }
  float C = 0.f;
  float4 p_cur = *(const float4*)(Pb + M_DIM + j0);   // row t=1 (always valid)
  if (Lb == 1) {
    float zs = (igrp == 0) ? (un.x + un.y) + (un.z + un.w) : 0.f;
    #pragma unroll
    for (int d = 1; d < 64; d <<= 1) zs += __shfl_xor(zs, d);
    if (lane == 0) red_sum[wid] = zs;
  }
  __syncthreads();

  if (Lb == 1) {
    if (tid == 0) {
      float s_ = 0.f, sy = 0.f;
      #pragma unroll
      for (int q = 0; q < 8; ++q) { s_ += red_sum[q]; sy += sY_sh[q]; }
      out[b] = __logf(s_) - sy;
    }
    return;
  }

// Sub-step. MODE: 0 = plain, 1 = APPLY renorm (t%4==1), 2 = SNAP (t%4==0).
#define CRF_STEP(S, MODE, PNEXT)                                           \
  {                                                                        \
    float4 ep;                                                             \
    ep.x = __expf(p_cur.x); ep.y = __expf(p_cur.y);                        \
    ep.z = __expf(p_cur.z); ep.w = __expf(p_cur.w);                        \
    if ((MODE) == 1) {                                                     \
      float4 ra = *(const float4*)&red[0];                                 \
      float4 rb = *(const float4*)&red[4];                                 \
      float Z = fmaxf(fmaxf(fmaxf(ra.x, ra.y), fmaxf(ra.z, ra.w)),         \
                      fmaxf(fmaxf(rb.x, rb.y), fmaxf(rb.z, rb.w)));        \
      C += __logf(Z);                                                      \
      float iZ = __builtin_amdgcn_rcpf(Z);                                 \
      ep.x *= iZ; ep.y *= iZ; ep.z *= iZ; ep.w *= iZ;                      \
    }                                                                      \
    const float4* u4 = (const float4*)(u_lds[cur]);                        \
    float acc[4] = {0.f, 0.f, 0.f, 0.f};                                   \
    {                                                                      \
      float4 uu = u4[f0];                                                  \
      const float ue[4] = {uu.x, uu.y, uu.z, uu.w};                        \
      _Pragma("unroll")                                                    \
      for (int e = 0; e < 4; ++e)                                          \
        _Pragma("unroll")                                                  \
        for (int jj = 0; jj < 4; ++jj)                                     \
          acc[jj] = fmaf(ue[e], w[e * 4 + jj], acc[jj]);                   \
    }                                                                      \
    {                                                                      \
      float4 uu = u4[f1];                                                  \
      const float ue[4] = {uu.x, uu.y, uu.z, uu.w};                        \
      _Pragma("unroll")                                                    \
      for (int e = 0; e < 4; ++e)                                          \
        _Pragma("unroll")                                                  \
        for (int jj = 0; jj < 4; ++jj)                                     \
          acc[jj] = fmaf(ue[e], w[16 + e * 4 + jj], acc[jj]);              \
    }                                                                      \
    _Pragma("unroll")                                                      \
    for (int jj = 0; jj < 4; ++jj) {                                       \
      float a = acc[jj];                                                   \
      a = dpp_add<0xB1>(a);                                                \
      a = dpp_add<0x4E>(a);                                                \
      a = dpp_add<0x141>(a);                                               \
      a = dpp_add<0x140>(a);                                               \
      acc[jj] = a;                                                         \
    }                                                                      \
    un.x = acc[0] * ep.x; un.y = acc[1] * ep.y;                            \
    un.z = acc[2] * ep.z; un.w = acc[3] * ep.w;                            \
    if (igrp == 0) *(float4*)&u_lds[cur ^ 1][j0] = un;                     \
    const bool last_ = (tb + (S) == Lb - 1);                               \
    if (last_) {                                                           \
      float zs = (igrp == 0) ? (un.x + un.y) + (un.z + un.w) : 0.f;        \
      _Pragma("unroll")                                                    \
      for (int d = 1; d < 64; d <<= 1) zs += __shfl_xor(zs, d);            \
      if (lane == 0) red_sum[wid] = zs;                                    \
    } else if ((MODE) == 2) {                                              \
      float zm = fmaxf(fmaxf(un.x, un.y), fmaxf(un.z, un.w));              \
      zm = fmaxf(zm, __shfl_xor(zm, 16));                                  \
      zm = fmaxf(zm, __shfl_xor(zm, 32));                                  \
      if (lane == 0) red[wid] = zm;                                        \
    }                                                                      \
    BARRIER_RELAXED();                                                     \
    if (last_) goto finish;                                                \
    p_cur = (PNEXT);                                                       \
    cur ^= 1;                                                              \
  }

  {
    int cur = 0;
    int tb  = 1;   // iteration handles steps tb..tb+7
    const float* Pq = Pb + j0;
    for (;;) {
      // Burst-prefetch P rows tb+1..tb+8 (clamped) into static float4 regs.
      float4 pn0, pn1, pn2, pn3, pn4, pn5, pn6, pn7;
      {
        int r;
        r = tb + 1; r = r < T_LEN ? r : T_LEN - 1; pn0 = *(const float4*)(Pq + r * M_DIM);
        r = tb + 2; r = r < T_LEN ? r : T_LEN - 1; pn1 = *(const float4*)(Pq + r * M_DIM);
        r = tb + 3; r = r < T_LEN ? r : T_LEN - 1; pn2 = *(const float4*)(Pq + r * M_DIM);
        r = tb + 4; r = r < T_LEN ? r : T_LEN - 1; pn3 = *(const float4*)(Pq + r * M_DIM);
        r = tb + 5; r = r < T_LEN ? r : T_LEN - 1; pn4 = *(const float4*)(Pq + r * M_DIM);
        r = tb + 6; r = r < T_LEN ? r : T_LEN - 1; pn5 = *(const float4*)(Pq + r * M_DIM);
        r = tb + 7; r = r < T_LEN ? r : T_LEN - 1; pn6 = *(const float4*)(Pq + r * M_DIM);
        r = tb + 8; r = r < T_LEN ? r : T_LEN - 1; pn7 = *(const float4*)(Pq + r * M_DIM);
      }
      // t mod 4 over sub-steps: 1,2,3,0,1,2,3,0
      CRF_STEP(0, 1, pn0)
      CRF_STEP(1, 0, pn1)
      CRF_STEP(2, 0, pn2)
      CRF_STEP(3, 2, pn3)
      CRF_STEP(4, 1, pn4)
      CRF_STEP(5, 0, pn5)
      CRF_STEP(6, 0, pn6)
      CRF_STEP(7, 2, pn7)
      tb += 8;
    }
  }

finish:
  if (tid == 0) {
    float s_ = 0.f, sy = 0.f;
    #pragma unroll
    for (int q = 0; q < 8; ++q) { s_ += red_sum[q]; sy += sY_sh[q]; }
    out[b] = __logf(s_) + C - sy;
  }
}

extern "C" void kernel_launch(void* const* d_in, const int* in_sizes, int n_in,
                              void* d_out, int out_size, void* d_ws, size_t ws_size,
                              hipStream_t stream) {
  const float* P = (const float*)d_in[0];
  const float* A = (const float*)d_in[1];
  const int*   Y = (const int*)d_in[2];
  const int*   L = (const int*)d_in[3];
  float* o = (float*)d_out;
  hipLaunchKernelGGL(crf_fwd, dim3(B_NUM), dim3(512), 0, stream, P, A, Y, L, o);
}